// Round 3
// baseline (1575.363 us; speedup 1.0000x reference)
//
#include <hip/hip_runtime.h>
#include <cstdint>
#include <cstddef>

// Problem constants (B,S,HID,NH,IM,E fixed by the reference)
#define B_    4
#define S_    2048
#define HID_  1024
#define NH_   4
#define HD_   256     // HID/NH
#define IM_   2048
#define E_    4
#define M_    8192    // B_*S_ tokens
#define NHG_  4       // heads per attention group (scores slab = NHG_*S_*S_*4 B)

typedef __bf16 bf16x8 __attribute__((ext_vector_type(8)));
typedef float  f32x4  __attribute__((ext_vector_type(4)));

__device__ __forceinline__ unsigned short f32_to_bf16(float f) {
  unsigned int u = __float_as_uint(f);
  u += 0x7fffu + ((u >> 16) & 1u);   // round-to-nearest-even
  return (unsigned short)(u >> 16);
}
__device__ __forceinline__ float bf16_to_f32(unsigned short s) {
  return __uint_as_float((unsigned int)s << 16);
}

// async 16B global->LDS DMA (global_load_lds_dwordx4). LDS dest is
// wave-uniform base + lane*16 (m104/m108) -> LDS layout must be contiguous
// in lane order, no padding.
__device__ __forceinline__ void gload16(const unsigned short* g, unsigned short* l) {
  __builtin_amdgcn_global_load_lds(
      (const __attribute__((address_space(1))) void*)g,
      (__attribute__((address_space(3))) void*)l, 16, 0, 0);
}

// ---------------- epilogue variants ----------------
#define EPI_F32      0   // C fp32 (attention scores), batched via strideCz
#define EPI_ELU_BF16 1   // bf16(elu(x)+1)  (q/k projections)
#define EPI_VT       2   // write V^T [b][h][d][s] bf16
#define EPI_PV_O     3   // write attn O into [token][h*HD+n] bf16
#define EPI_WO       4   // out2 = add_src + acc  (h1 into d_out)
#define EPI_SILU     5   // c_bf16 = bf16(silu(acc))          (gate GEMM)
#define EPI_GU       6   // gu_out = bf16(bf16(gu_out) * acc) (up GEMM, in place)
#define EPI_DOWN     7   // out2 += acc * rw[token][expert]

struct EpiAux {
  float* c_f32;
  unsigned short* c_bf16;
  const float* add_src;       // hidden (WO)
  float* out2;                // d_out (WO/DOWN)
  unsigned short* gu_out;     // gu bf16 (GU)
  const float* rw;            // routing weights (DOWN)
  int expert;
  long long strideCz;
  int ldc;
};

// Generic batched GEMM: C[z] = A[z] (MxK, row-major, lda) @ B[z]^T (B stored
// as BT: N rows of K, ldb).  Per-z operand offsets: off = (z'>>zshift)*so +
// (z'&zmask)*si with z' = blockIdx.z + zb.
// 128x128 tile, BK=32, 4 waves x (4x4) 16x16x32 bf16 MFMA fragments.
// Staging via global_load_lds width=16 (m97 structure, ~874 TF-class).
template<int EPI>
__global__ __launch_bounds__(256) void gemm_bf16k(
    const unsigned short* __restrict__ A, int lda, long long sAo, long long sAi, int zbA,
    const unsigned short* __restrict__ B, int ldb, long long sBo, long long sBi, int zbB,
    int zshift, int zmask, int zbC, int K, EpiAux aux)
{
  // UNPADDED: 128 rows x 32 k x 2B = 8 KiB each; required by global_load_lds
  __shared__ unsigned short As[128 * 32];
  __shared__ unsigned short Bs[128 * 32];

  const int t  = threadIdx.x;
  const int m0 = blockIdx.y * 128, n0 = blockIdx.x * 128;
  const int z  = blockIdx.z;
  const int zA = z + zbA, zB = z + zbB, zC = z + zbC;
  const unsigned short* Ab = A + (long long)(zA >> zshift) * sAo + (long long)(zA & zmask) * sAi;
  const unsigned short* Bb = B + (long long)(zB >> zshift) * sBo + (long long)(zB & zmask) * sBi;

  const int lane = t & 63, wave = t >> 6;
  const int wm = (wave >> 1) * 64, wn = (wave & 1) * 64;
  const int lrow = lane & 15, quad = lane >> 4;

  f32x4 acc[4][4] = {};

  // staging: 1 KiB chunk = 16 rows (64 B/row); lane i -> row 16c+(i>>2),
  // k-elem (i&3)*8.  Wave w stages chunks {w, w+4} of A and of B.
  const int srow = lane >> 2;         // 0..15
  const int sko  = (lane & 3) * 8;    // 0/8/16/24
  const unsigned short* aRow0 = Ab + (long long)(m0 + wave * 16      + srow) * lda + sko;
  const unsigned short* aRow1 = Ab + (long long)(m0 + (wave + 4) * 16 + srow) * lda + sko;
  const unsigned short* bRow0 = Bb + (long long)(n0 + wave * 16      + srow) * ldb + sko;
  const unsigned short* bRow1 = Bb + (long long)(n0 + (wave + 4) * 16 + srow) * ldb + sko;
  unsigned short* asDst0 = &As[(wave * 16) * 32];        // wave-uniform bases
  unsigned short* asDst1 = &As[((wave + 4) * 16) * 32];
  unsigned short* bsDst0 = &Bs[(wave * 16) * 32];
  unsigned short* bsDst1 = &Bs[((wave + 4) * 16) * 32];

  for (int kk = 0; kk < K; kk += 32) {
    __syncthreads();                 // prior tile's ds_reads done everywhere
    gload16(aRow0 + kk, asDst0);
    gload16(aRow1 + kk, asDst1);
    gload16(bRow0 + kk, bsDst0);
    gload16(bRow1 + kk, bsDst1);
    __syncthreads();                 // vmcnt(0) drained -> LDS tile valid
    bf16x8 af[4], bfr[4];
    #pragma unroll
    for (int i = 0; i < 4; ++i) {
      af[i]  = *reinterpret_cast<const bf16x8*>(&As[(wm + i * 16 + lrow) * 32 + quad * 8]);
      bfr[i] = *reinterpret_cast<const bf16x8*>(&Bs[(wn + i * 16 + lrow) * 32 + quad * 8]);
    }
    #pragma unroll
    for (int i = 0; i < 4; ++i)
      #pragma unroll
      for (int j = 0; j < 4; ++j)
        acc[i][j] = __builtin_amdgcn_mfma_f32_16x16x32_bf16(af[i], bfr[j], acc[i][j], 0, 0, 0);
  }

  // epilogue: D row = quad*4+r, col = lane&15  [verified layout, m89/m91]
  #pragma unroll
  for (int mi = 0; mi < 4; ++mi) {
    #pragma unroll
    for (int ni = 0; ni < 4; ++ni) {
      #pragma unroll
      for (int r = 0; r < 4; ++r) {
        const int gm = m0 + wm + mi * 16 + quad * 4 + r;
        const int gn = n0 + wn + ni * 16 + lrow;
        const float val = acc[mi][ni][r];
        if (EPI == EPI_F32) {
          aux.c_f32[(long long)zC * aux.strideCz + (long long)gm * aux.ldc + gn] = val;
        } else if (EPI == EPI_ELU_BF16) {
          const float e = val > 0.f ? val + 1.f : __expf(val);   // elu(x)+1
          aux.c_bf16[(long long)gm * aux.ldc + gn] = f32_to_bf16(e);
        } else if (EPI == EPI_VT) {
          const int b = gm >> 11, s = gm & (S_ - 1);
          const int h = gn >> 8, d = gn & (HD_ - 1);
          aux.c_bf16[((long long)(b * NH_ + h) * HD_ + d) * S_ + s] = f32_to_bf16(val);
        } else if (EPI == EPI_PV_O) {
          const int b = zC >> 2, h = zC & (NH_ - 1);
          aux.c_bf16[((long long)(b * S_ + gm)) * HID_ + h * HD_ + gn] = f32_to_bf16(val);
        } else if (EPI == EPI_WO) {
          const long long idx = (long long)gm * HID_ + gn;
          aux.out2[idx] = val + aux.add_src[idx];
        } else if (EPI == EPI_SILU) {
          const long long idx = (long long)gm * aux.ldc + gn;
          const float sg = val / (1.f + __expf(-val));    // silu
          aux.c_bf16[idx] = f32_to_bf16(sg);
        } else if (EPI == EPI_GU) {
          const long long idx = (long long)gm * aux.ldc + gn;
          const float sg = bf16_to_f32(aux.gu_out[idx]);  // silu(g), same idx
          aux.gu_out[idx] = f32_to_bf16(sg * val);
        } else if (EPI == EPI_DOWN) {
          const long long idx = (long long)gm * HID_ + gn;
          aux.out2[idx] += val * aux.rw[(long long)gm * E_ + aux.expert];
        }
      }
    }
  }
}

// fp32 [R][C] -> bf16 [C][R], batched over blockIdx.z (stride R*C both sides)
__global__ void transpose_cast_k(const float* __restrict__ in,
                                 unsigned short* __restrict__ out, int R, int C)
{
  __shared__ float tile[32][33];
  const long long bo = (long long)blockIdx.z * R * C;
  const int c0 = blockIdx.x * 32, r0 = blockIdx.y * 32;
  const int tx = threadIdx.x, ty = threadIdx.y;
  #pragma unroll
  for (int i = 0; i < 32; i += 8)
    tile[ty + i][tx] = in[bo + (long long)(r0 + ty + i) * C + c0 + tx];
  __syncthreads();
  #pragma unroll
  for (int i = 0; i < 32; i += 8)
    out[bo + (long long)(c0 + ty + i) * R + r0 + tx] = f32_to_bf16(tile[tx][ty + i]);
}

// rmsnorm row (HID=1024) + weight + bf16 cast; one block per token
__global__ __launch_bounds__(256) void rmsnorm_cast_k(
    const float* __restrict__ x, const float* __restrict__ w,
    unsigned short* __restrict__ out)
{
  __shared__ float red[4];
  const int row = blockIdx.x, t = threadIdx.x;
  const float4 v = reinterpret_cast<const float4*>(x + (long long)row * HID_)[t];
  float ss = v.x * v.x + v.y * v.y + v.z * v.z + v.w * v.w;
  #pragma unroll
  for (int off = 32; off > 0; off >>= 1) ss += __shfl_down(ss, off, 64);
  if ((t & 63) == 0) red[t >> 6] = ss;
  __syncthreads();
  ss = red[0] + red[1] + red[2] + red[3];
  const float inv = rsqrtf(ss * (1.0f / HID_) + 1e-6f);
  const float4 wv = reinterpret_cast<const float4*>(w)[t];
  ushort4 o;
  o.x = f32_to_bf16(v.x * inv * wv.x);
  o.y = f32_to_bf16(v.y * inv * wv.y);
  o.z = f32_to_bf16(v.z * inv * wv.z);
  o.w = f32_to_bf16(v.w * inv * wv.w);
  reinterpret_cast<ushort4*>(out + (long long)row * HID_)[t] = o;
}

// softmax over a 2048-wide fp32 row; writes P bf16 IN PLACE over the row
__global__ __launch_bounds__(256) void softmax_rows_k(float* __restrict__ scores)
{
  __shared__ float red[4];
  const long long rbase = ((long long)blockIdx.y * S_ + blockIdx.x) * S_;
  float* row = scores + rbase;
  const int t = threadIdx.x;
  float v[8];
  #pragma unroll
  for (int i = 0; i < 8; ++i) v[i] = row[t + i * 256];
  float m = v[0];
  #pragma unroll
  for (int i = 1; i < 8; ++i) m = fmaxf(m, v[i]);
  #pragma unroll
  for (int off = 32; off > 0; off >>= 1) m = fmaxf(m, __shfl_down(m, off, 64));
  if ((t & 63) == 0) red[t >> 6] = m;
  __syncthreads();
  m = fmaxf(fmaxf(red[0], red[1]), fmaxf(red[2], red[3]));
  __syncthreads();
  float s = 0.f;
  #pragma unroll
  for (int i = 0; i < 8; ++i) { v[i] = __expf(v[i] - m); s += v[i]; }
  #pragma unroll
  for (int off = 32; off > 0; off >>= 1) s += __shfl_down(s, off, 64);
  if ((t & 63) == 0) red[t >> 6] = s;
  __syncthreads();
  const float inv = 1.0f / (red[0] + red[1] + red[2] + red[3]);
  unsigned short* prow = reinterpret_cast<unsigned short*>(scores) + rbase * 2;
  #pragma unroll
  for (int i = 0; i < 8; ++i) prow[t + i * 256] = f32_to_bf16(v[i] * inv);
}

// router: fp32 rms(h1)*ln2w @ router_w + b, softmax over E=4. One wave/token.
__global__ __launch_bounds__(256) void router_k(
    const float* __restrict__ h1, const float* __restrict__ ln2w,
    const float* __restrict__ rwgt, const float* __restrict__ rbias,
    float* __restrict__ rw)
{
  const int wv = threadIdx.x >> 6, lane = threadIdx.x & 63;
  const long long m = (long long)blockIdx.x * 4 + wv;
  const float* xr = h1 + m * HID_;
  float xv[16];
  float ss = 0.f;
  #pragma unroll
  for (int i = 0; i < 16; ++i) { xv[i] = xr[lane + i * 64]; ss += xv[i] * xv[i]; }
  #pragma unroll
  for (int off = 32; off > 0; off >>= 1) ss += __shfl_down(ss, off, 64);
  ss = __shfl(ss, 0, 64);
  const float inv = rsqrtf(ss * (1.0f / HID_) + 1e-6f);
  float l0 = 0, l1 = 0, l2 = 0, l3 = 0;
  #pragma unroll
  for (int i = 0; i < 16; ++i) {
    const int k = lane + i * 64;
    const float xn = xv[i] * inv * ln2w[k];
    const float4 wr = reinterpret_cast<const float4*>(rwgt)[k];
    l0 += xn * wr.x; l1 += xn * wr.y; l2 += xn * wr.z; l3 += xn * wr.w;
  }
  #pragma unroll
  for (int off = 32; off > 0; off >>= 1) {
    l0 += __shfl_down(l0, off, 64);
    l1 += __shfl_down(l1, off, 64);
    l2 += __shfl_down(l2, off, 64);
    l3 += __shfl_down(l3, off, 64);
  }
  if (lane == 0) {
    l0 += rbias[0]; l1 += rbias[1]; l2 += rbias[2]; l3 += rbias[3];
    const float mx = fmaxf(fmaxf(l0, l1), fmaxf(l2, l3));
    const float e0 = __expf(l0 - mx), e1 = __expf(l1 - mx);
    const float e2 = __expf(l2 - mx), e3 = __expf(l3 - mx);
    const float is = 1.0f / (e0 + e1 + e2 + e3);
    reinterpret_cast<float4*>(rw)[m] = make_float4(e0 * is, e1 * is, e2 * is, e3 * is);
  }
}

// balance loss: single block, deterministic
__global__ __launch_bounds__(256) void balance_k(const float* __restrict__ rw,
                                                 float* __restrict__ out_scalar)
{
  __shared__ float red[4];
  float acc = 0.f;
  for (int it = threadIdx.x; it < S_ * E_; it += 256) {
    const int s = it >> 2, e = it & 3;
    float mr = 0.f;
    #pragma unroll
    for (int b = 0; b < B_; ++b) mr += rw[((long long)b * S_ + s) * E_ + e];
    mr *= (1.0f / B_);
    const float d = mr - 1.0f / E_;
    acc += d * d;
  }
  #pragma unroll
  for (int off = 32; off > 0; off >>= 1) acc += __shfl_down(acc, off, 64);
  if ((threadIdx.x & 63) == 0) red[threadIdx.x >> 6] = acc;
  __syncthreads();
  if (threadIdx.x == 0)
    out_scalar[0] = (red[0] + red[1] + red[2] + red[3]) * (0.01f / (S_ * E_));
}

extern "C" void kernel_launch(void* const* d_in, const int* in_sizes, int n_in,
                              void* d_out, int out_size, void* d_ws, size_t ws_size,
                              hipStream_t stream)
{
  const float* hidden   = (const float*)d_in[0];
  const float* ln1w     = (const float*)d_in[1];
  const float* wq       = (const float*)d_in[2];
  const float* wk       = (const float*)d_in[3];
  const float* wv       = (const float*)d_in[4];
  const float* wo       = (const float*)d_in[5];
  const float* ln2w     = (const float*)d_in[6];
  const float* router_w = (const float*)d_in[7];
  const float* router_b = (const float*)d_in[8];
  const float* gate_w   = (const float*)d_in[9];
  const float* up_w     = (const float*)d_in[10];
  const float* down_w   = (const float*)d_in[11];
  float* out = (float*)d_out;   // h1 lives here; MoE accumulates in place

  // ---- lean workspace layout: 136.1 MiB total ----
  char* ws = (char*)d_ws;
  size_t off = 0;
  auto carve = [&](size_t bytes) {
    off = (off + 255) & ~(size_t)255;
    char* p = ws + off;
    off += bytes;
    return p;
  };
  unsigned short* wqT   = (unsigned short*)carve((size_t)HID_ * HID_ * 2);  // 2 MiB
  unsigned short* wkT   = (unsigned short*)carve((size_t)HID_ * HID_ * 2);
  unsigned short* wvT   = (unsigned short*)carve((size_t)HID_ * HID_ * 2);
  unsigned short* woT   = (unsigned short*)carve((size_t)HID_ * HID_ * 2);
  unsigned short* x_bf  = (unsigned short*)carve((size_t)M_ * HID_ * 2);    // 16 MiB, reused as o_bf
  unsigned short* qb    = (unsigned short*)carve((size_t)M_ * HID_ * 2);    // 16 MiB, reused as x2_bf
  unsigned short* kb    = (unsigned short*)carve((size_t)M_ * HID_ * 2);    // 16 MiB \ reused as gu (32 MiB,
  unsigned short* vT    = (unsigned short*)carve((size_t)M_ * HID_ * 2);    // 16 MiB /  contiguous)
  float*          rwbuf = (float*)carve((size_t)M_ * E_ * 4);               // 128 KiB
  char*           ubase = carve((size_t)NHG_ * S_ * S_ * 4);                // 64 MiB union
  float*          scores = (float*)ubase;
  unsigned short* gateT = (unsigned short*)(ubase);                          // 16 MiB
  unsigned short* upT   = (unsigned short*)(ubase + (size_t)16 * 1024 * 1024);
  unsigned short* downT = (unsigned short*)(ubase + (size_t)32 * 1024 * 1024);
  unsigned short* o_bf  = x_bf;
  unsigned short* x2_bf = qb;
  unsigned short* gu    = kb;   // spans kb+vT = 32 MiB

  const dim3 blk256(256), blkT(32, 8);

  // 1) attention weights -> bf16 B^T
  transpose_cast_k<<<dim3(32, 32, 1), blkT, 0, stream>>>(wq, wqT, HID_, HID_);
  transpose_cast_k<<<dim3(32, 32, 1), blkT, 0, stream>>>(wk, wkT, HID_, HID_);
  transpose_cast_k<<<dim3(32, 32, 1), blkT, 0, stream>>>(wv, wvT, HID_, HID_);
  transpose_cast_k<<<dim3(32, 32, 1), blkT, 0, stream>>>(wo, woT, HID_, HID_);

  // 2) x = bf16(rms(hidden, ln1_w))
  rmsnorm_cast_k<<<M_, blk256, 0, stream>>>(hidden, ln1w, x_bf);

  // 3) Q/K with fused elu+1, V written transposed
  {
    EpiAux a{}; a.c_bf16 = qb; a.ldc = HID_;
    gemm_bf16k<EPI_ELU_BF16><<<dim3(8, 64, 1), blk256, 0, stream>>>(
        x_bf, HID_, 0, 0, 0, wqT, HID_, 0, 0, 0, 0, 0, 0, HID_, a);
  }
  {
    EpiAux a{}; a.c_bf16 = kb; a.ldc = HID_;
    gemm_bf16k<EPI_ELU_BF16><<<dim3(8, 64, 1), blk256, 0, stream>>>(
        x_bf, HID_, 0, 0, 0, wkT, HID_, 0, 0, 0, 0, 0, 0, HID_, a);
  }
  {
    EpiAux a{}; a.c_bf16 = vT;
    gemm_bf16k<EPI_VT><<<dim3(8, 64, 1), blk256, 0, stream>>>(
        x_bf, HID_, 0, 0, 0, wvT, HID_, 0, 0, 0, 0, 0, 0, HID_, a);
  }

  // 4) attention, NHG_=4 heads per group; scores slab reused per group
  for (int grp = 0; grp < 16 / NHG_; ++grp) {
    EpiAux as{}; as.c_f32 = scores; as.ldc = S_; as.strideCz = (long long)S_ * S_;
    gemm_bf16k<EPI_F32><<<dim3(16, 16, NHG_), blk256, 0, stream>>>(
        qb, HID_, (long long)S_ * HID_, HD_, grp * NHG_,
        kb, HID_, (long long)S_ * HID_, HD_, grp * NHG_,
        2, 3, 0, HD_, as);
    softmax_rows_k<<<dim3(S_, NHG_, 1), blk256, 0, stream>>>(scores);
    EpiAux ap{}; ap.c_bf16 = o_bf;
    gemm_bf16k<EPI_PV_O><<<dim3(2, 16, NHG_), blk256, 0, stream>>>(
        (const unsigned short*)scores, 2 * S_, (long long)S_ * 2 * S_, 0, 0,
        vT, S_, (long long)HD_ * S_, 0, grp * NHG_,
        0, 0, grp * NHG_, S_, ap);
  }

  // 5) MoE weights -> bf16 B^T, into the now-dead scores slab
  transpose_cast_k<<<dim3(64, 32, E_), blkT, 0, stream>>>(gate_w, gateT, HID_, IM_);
  transpose_cast_k<<<dim3(64, 32, E_), blkT, 0, stream>>>(up_w,   upT,   HID_, IM_);
  transpose_cast_k<<<dim3(32, 64, E_), blkT, 0, stream>>>(down_w, downT, IM_, HID_);

  // 6) h1 = hidden + O @ wo, written straight into d_out
  {
    EpiAux a{}; a.add_src = hidden; a.out2 = out;
    gemm_bf16k<EPI_WO><<<dim3(8, 64, 1), blk256, 0, stream>>>(
        o_bf, HID_, 0, 0, 0, woT, HID_, 0, 0, 0, 0, 0, 0, HID_, a);
  }

  // 7) x2 = bf16(rms(h1, ln2_w)); router (fp32); balance loss scalar
  rmsnorm_cast_k<<<M_, blk256, 0, stream>>>(out, ln2w, x2_bf);
  router_k<<<M_ / 4, blk256, 0, stream>>>(out, ln2w, router_w, router_b, rwbuf);
  balance_k<<<1, blk256, 0, stream>>>(rwbuf, out + (size_t)M_ * HID_);

  // 8) dense MoE: gate -> silu bf16 (gu); up -> gu *= acc; down -> out += acc*rw
  for (int i = 0; i < E_; ++i) {
    EpiAux ag{}; ag.c_bf16 = gu; ag.ldc = IM_;
    gemm_bf16k<EPI_SILU><<<dim3(16, 64, 1), blk256, 0, stream>>>(
        x2_bf, HID_, 0, 0, 0, gateT + (size_t)i * IM_ * HID_, HID_, 0, 0, 0,
        0, 0, 0, HID_, ag);
    EpiAux au{}; au.gu_out = gu; au.ldc = IM_;
    gemm_bf16k<EPI_GU><<<dim3(16, 64, 1), blk256, 0, stream>>>(
        x2_bf, HID_, 0, 0, 0, upT + (size_t)i * IM_ * HID_, HID_, 0, 0, 0,
        0, 0, 0, HID_, au);
    EpiAux ad{}; ad.out2 = out; ad.rw = rwbuf; ad.expert = i;
    gemm_bf16k<EPI_DOWN><<<dim3(8, 64, 1), blk256, 0, stream>>>(
        gu, IM_, 0, 0, 0, downT + (size_t)i * HID_ * IM_, IM_, 0, 0, 0,
        0, 0, 0, IM_, ad);
  }
}

// Round 4
// 1194.516 us; speedup vs baseline: 1.3188x; 1.3188x over previous
//
#include <hip/hip_runtime.h>
#include <cstdint>
#include <cstddef>

// Problem constants (B,S,HID,NH,IM,E fixed by the reference)
#define B_    4
#define S_    2048
#define HID_  1024
#define NH_   4
#define HD_   256     // HID/NH
#define IM_   2048
#define E_    4
#define M_    8192    // B_*S_ tokens
#define NHG_  4       // heads per attention group

typedef __bf16 bf16x8 __attribute__((ext_vector_type(8)));
typedef float  f32x4  __attribute__((ext_vector_type(4)));

__device__ __forceinline__ unsigned short f32_to_bf16(float f) {
  unsigned int u = __float_as_uint(f);
  u += 0x7fffu + ((u >> 16) & 1u);   // round-to-nearest-even
  return (unsigned short)(u >> 16);
}
__device__ __forceinline__ float bf16_to_f32(unsigned short s) {
  return __uint_as_float((unsigned int)s << 16);
}

// async 16B global->LDS DMA (global_load_lds_dwordx4). LDS dest is
// wave-uniform base + lane*16 -> LDS layout contiguous in lane order.
__device__ __forceinline__ void gload16(const unsigned short* g, unsigned short* l) {
  __builtin_amdgcn_global_load_lds(
      (const __attribute__((address_space(1))) void*)g,
      (__attribute__((address_space(3))) void*)l, 16, 0, 0);
}

// XCD-aware swizzle: contiguous y-bands per XCD (dispatch round-robins flat id
// over 8 XCDs). Requires gridDim.x*gridDim.y % 8 == 0 and gridDim.y % 8 == 0
// OR small grids where gy<8*? -- here all call sites have gx*gy % 8 == 0 and
// gy % 8 == 0 or gy=16 (rpx=2). Speed-only heuristic, never affects result.
__device__ __forceinline__ void swizzle_xy(int& bx, int& by) {
  const int gx = gridDim.x, gy = gridDim.y;
  const int flat = blockIdx.x + blockIdx.y * gx;
  const int xcd = flat & 7, i = flat >> 3;
  const int rpx = gy >> 3;          // y-rows per XCD
  bx = i % gx;
  by = xcd * rpx + i / gx;
}

// ---------------- epilogue variants ----------------
#define EPI_F32      0   // C fp32 (attention scores), batched via strideCz
#define EPI_ELU_BF16 1   // bf16(elu(x)+1)  (q/k projections)
#define EPI_VT       2   // write V^T [b][h][d][s] bf16
#define EPI_PV_O     3   // write attn O into [token][h*HD+n] bf16
#define EPI_WO       4   // out2 = add_src + acc  (h1 into d_out)
#define EPI_DOWN     5   // out2 += acc * rw[token][expert]

struct EpiAux {
  float* c_f32;
  unsigned short* c_bf16;
  const float* add_src;       // hidden (WO)
  float* out2;                // d_out (WO/DOWN)
  const float* rw;            // routing weights (DOWN)
  int expert;
  long long strideCz;
  int ldc;
};

// Generic batched GEMM: C[z] = A[z] (MxK, row-major, lda) @ B[z]^T.
// 128x128 tile, BK=32, 4 waves x (4x4) 16x16x32 bf16 MFMA fragments.
// Double-buffered LDS, one-iteration-ahead async global_load_lds prefetch:
// prefetch is issued AFTER the barrier so the next barrier's vmcnt(0) drains
// loads that had a full compute phase to land (hides the global round-trip).
template<int EPI>
__global__ __launch_bounds__(256) void gemm_bf16k(
    const unsigned short* __restrict__ A, int lda, long long sAo, long long sAi, int zbA,
    const unsigned short* __restrict__ B, int ldb, long long sBo, long long sBi, int zbB,
    int zshift, int zmask, int zbC, int K, EpiAux aux)
{
  __shared__ unsigned short As[2][128 * 32];
  __shared__ unsigned short Bs[2][128 * 32];

  const int t = threadIdx.x;
  int bx, by;
  swizzle_xy(bx, by);
  const int m0 = by * 128, n0 = bx * 128;
  const int z  = blockIdx.z;
  const int zA = z + zbA, zB = z + zbB, zC = z + zbC;
  const unsigned short* Ab = A + (long long)(zA >> zshift) * sAo + (long long)(zA & zmask) * sAi;
  const unsigned short* Bb = B + (long long)(zB >> zshift) * sBo + (long long)(zB & zmask) * sBi;

  const int lane = t & 63, wave = t >> 6;
  const int wm = (wave >> 1) * 64, wn = (wave & 1) * 64;
  const int lrow = lane & 15, quad = lane >> 4;

  f32x4 acc[4][4] = {};

  // staging: 1 KiB chunk = 16 rows x 64 B; wave w stages chunks {w, w+4}
  const int srow = lane >> 2;         // 0..15
  const int sko  = (lane & 3) * 8;    // k-elem 0/8/16/24
  const unsigned short* aRow0 = Ab + (long long)(m0 + wave * 16       + srow) * lda + sko;
  const unsigned short* aRow1 = Ab + (long long)(m0 + (wave + 4) * 16 + srow) * lda + sko;
  const unsigned short* bRow0 = Bb + (long long)(n0 + wave * 16       + srow) * ldb + sko;
  const unsigned short* bRow1 = Bb + (long long)(n0 + (wave + 4) * 16 + srow) * ldb + sko;
  const int dst0 = (wave * 16) * 32, dst1 = ((wave + 4) * 16) * 32;

  // prologue: stage tile 0 into buffer 0
  gload16(aRow0, &As[0][dst0]);
  gload16(aRow1, &As[0][dst1]);
  gload16(bRow0, &Bs[0][dst0]);
  gload16(bRow1, &Bs[0][dst1]);

  int cur = 0;
  for (int kk = 0; kk < K; kk += 32, cur ^= 1) {
    __syncthreads();                 // drains DMA for buf[cur]; frees buf[cur^1]
    if (kk + 32 < K) {               // prefetch next tile into the other buffer
      const int nxt = cur ^ 1, k2 = kk + 32;
      gload16(aRow0 + k2, &As[nxt][dst0]);
      gload16(aRow1 + k2, &As[nxt][dst1]);
      gload16(bRow0 + k2, &Bs[nxt][dst0]);
      gload16(bRow1 + k2, &Bs[nxt][dst1]);
    }
    bf16x8 af[4], bfr[4];
    #pragma unroll
    for (int i = 0; i < 4; ++i) {
      af[i]  = *reinterpret_cast<const bf16x8*>(&As[cur][(wm + i * 16 + lrow) * 32 + quad * 8]);
      bfr[i] = *reinterpret_cast<const bf16x8*>(&Bs[cur][(wn + i * 16 + lrow) * 32 + quad * 8]);
    }
    #pragma unroll
    for (int i = 0; i < 4; ++i)
      #pragma unroll
      for (int j = 0; j < 4; ++j)
        acc[i][j] = __builtin_amdgcn_mfma_f32_16x16x32_bf16(af[i], bfr[j], acc[i][j], 0, 0, 0);
  }

  // epilogue: D row = quad*4+r, col = lane&15
  #pragma unroll
  for (int mi = 0; mi < 4; ++mi) {
    #pragma unroll
    for (int ni = 0; ni < 4; ++ni) {
      #pragma unroll
      for (int r = 0; r < 4; ++r) {
        const int gm = m0 + wm + mi * 16 + quad * 4 + r;
        const int gn = n0 + wn + ni * 16 + lrow;
        const float val = acc[mi][ni][r];
        if (EPI == EPI_F32) {
          aux.c_f32[(long long)zC * aux.strideCz + (long long)gm * aux.ldc + gn] = val;
        } else if (EPI == EPI_ELU_BF16) {
          const float e = val > 0.f ? val + 1.f : __expf(val);   // elu(x)+1
          aux.c_bf16[(long long)gm * aux.ldc + gn] = f32_to_bf16(e);
        } else if (EPI == EPI_VT) {
          const int b = gm >> 11, s = gm & (S_ - 1);
          const int h = gn >> 8, d = gn & (HD_ - 1);
          aux.c_bf16[((long long)(b * NH_ + h) * HD_ + d) * S_ + s] = f32_to_bf16(val);
        } else if (EPI == EPI_PV_O) {
          const int b = zC >> 2, h = zC & (NH_ - 1);
          aux.c_bf16[((long long)(b * S_ + gm)) * HID_ + h * HD_ + gn] = f32_to_bf16(val);
        } else if (EPI == EPI_WO) {
          const long long idx = (long long)gm * HID_ + gn;
          aux.out2[idx] = val + aux.add_src[idx];
        } else if (EPI == EPI_DOWN) {
          const long long idx = (long long)gm * HID_ + gn;
          aux.out2[idx] += val * aux.rw[(long long)gm * E_ + aux.expert];
        }
      }
    }
  }
}

// Fused gate+up GEMM for one expert: shares the A (x2) staging, computes two
// accumulator sets, writes gu = bf16(silu(g) * u) directly. K = HID_ fixed.
// 32 MFMA per barrier, 12 chunks staged per step (vs 2x[16 MFMA / 8 chunks]).
__global__ __launch_bounds__(256, 2) void gemm_gu_k(
    const unsigned short* __restrict__ A,    // x2_bf [M_][HID_]
    const unsigned short* __restrict__ Bg,   // gateT_e [IM_][HID_]
    const unsigned short* __restrict__ Bu,   // upT_e   [IM_][HID_]
    unsigned short* __restrict__ gu)         // [M_][IM_]
{
  __shared__ unsigned short As[2][128 * 32];
  __shared__ unsigned short Bgs[2][128 * 32];
  __shared__ unsigned short Bus[2][128 * 32];

  const int t = threadIdx.x;
  int bx, by;
  swizzle_xy(bx, by);
  const int m0 = by * 128, n0 = bx * 128;

  const int lane = t & 63, wave = t >> 6;
  const int wm = (wave >> 1) * 64, wn = (wave & 1) * 64;
  const int lrow = lane & 15, quad = lane >> 4;

  f32x4 accg[4][4] = {}, accu[4][4] = {};

  const int srow = lane >> 2;
  const int sko  = (lane & 3) * 8;
  const unsigned short* aRow0 = A  + (long long)(m0 + wave * 16       + srow) * HID_ + sko;
  const unsigned short* aRow1 = A  + (long long)(m0 + (wave + 4) * 16 + srow) * HID_ + sko;
  const unsigned short* gRow0 = Bg + (long long)(n0 + wave * 16       + srow) * HID_ + sko;
  const unsigned short* gRow1 = Bg + (long long)(n0 + (wave + 4) * 16 + srow) * HID_ + sko;
  const unsigned short* uRow0 = Bu + (long long)(n0 + wave * 16       + srow) * HID_ + sko;
  const unsigned short* uRow1 = Bu + (long long)(n0 + (wave + 4) * 16 + srow) * HID_ + sko;
  const int dst0 = (wave * 16) * 32, dst1 = ((wave + 4) * 16) * 32;

  gload16(aRow0, &As[0][dst0]);
  gload16(aRow1, &As[0][dst1]);
  gload16(gRow0, &Bgs[0][dst0]);
  gload16(gRow1, &Bgs[0][dst1]);
  gload16(uRow0, &Bus[0][dst0]);
  gload16(uRow1, &Bus[0][dst1]);

  int cur = 0;
  for (int kk = 0; kk < HID_; kk += 32, cur ^= 1) {
    __syncthreads();
    if (kk + 32 < HID_) {
      const int nxt = cur ^ 1, k2 = kk + 32;
      gload16(aRow0 + k2, &As[nxt][dst0]);
      gload16(aRow1 + k2, &As[nxt][dst1]);
      gload16(gRow0 + k2, &Bgs[nxt][dst0]);
      gload16(gRow1 + k2, &Bgs[nxt][dst1]);
      gload16(uRow0 + k2, &Bus[nxt][dst0]);
      gload16(uRow1 + k2, &Bus[nxt][dst1]);
    }
    bf16x8 af[4], bg[4], bu[4];
    #pragma unroll
    for (int i = 0; i < 4; ++i) {
      af[i] = *reinterpret_cast<const bf16x8*>(&As[cur][(wm + i * 16 + lrow) * 32 + quad * 8]);
      bg[i] = *reinterpret_cast<const bf16x8*>(&Bgs[cur][(wn + i * 16 + lrow) * 32 + quad * 8]);
      bu[i] = *reinterpret_cast<const bf16x8*>(&Bus[cur][(wn + i * 16 + lrow) * 32 + quad * 8]);
    }
    #pragma unroll
    for (int i = 0; i < 4; ++i)
      #pragma unroll
      for (int j = 0; j < 4; ++j) {
        accg[i][j] = __builtin_amdgcn_mfma_f32_16x16x32_bf16(af[i], bg[j], accg[i][j], 0, 0, 0);
        accu[i][j] = __builtin_amdgcn_mfma_f32_16x16x32_bf16(af[i], bu[j], accu[i][j], 0, 0, 0);
      }
  }

  #pragma unroll
  for (int mi = 0; mi < 4; ++mi)
    #pragma unroll
    for (int ni = 0; ni < 4; ++ni)
      #pragma unroll
      for (int r = 0; r < 4; ++r) {
        const int gm = m0 + wm + mi * 16 + quad * 4 + r;
        const int gn = n0 + wn + ni * 16 + lrow;
        const float g = accg[mi][ni][r];
        const float u = accu[mi][ni][r];
        const float sg = g / (1.f + __expf(-g));    // silu(g), fp32
        gu[(long long)gm * IM_ + gn] = f32_to_bf16(sg * u);
      }
}

// fp32 [R][C] -> bf16 [C][R], batched over blockIdx.z (stride R*C both sides)
__global__ void transpose_cast_k(const float* __restrict__ in,
                                 unsigned short* __restrict__ out, int R, int C)
{
  __shared__ float tile[32][33];
  const long long bo = (long long)blockIdx.z * R * C;
  const int c0 = blockIdx.x * 32, r0 = blockIdx.y * 32;
  const int tx = threadIdx.x, ty = threadIdx.y;
  #pragma unroll
  for (int i = 0; i < 32; i += 8)
    tile[ty + i][tx] = in[bo + (long long)(r0 + ty + i) * C + c0 + tx];
  __syncthreads();
  #pragma unroll
  for (int i = 0; i < 32; i += 8)
    out[bo + (long long)(c0 + ty + i) * R + r0 + tx] = f32_to_bf16(tile[tx][ty + i]);
}

// rmsnorm row (HID=1024) + weight + bf16 cast; one block per token
__global__ __launch_bounds__(256) void rmsnorm_cast_k(
    const float* __restrict__ x, const float* __restrict__ w,
    unsigned short* __restrict__ out)
{
  __shared__ float red[4];
  const int row = blockIdx.x, t = threadIdx.x;
  const float4 v = reinterpret_cast<const float4*>(x + (long long)row * HID_)[t];
  float ss = v.x * v.x + v.y * v.y + v.z * v.z + v.w * v.w;
  #pragma unroll
  for (int off = 32; off > 0; off >>= 1) ss += __shfl_down(ss, off, 64);
  if ((t & 63) == 0) red[t >> 6] = ss;
  __syncthreads();
  ss = red[0] + red[1] + red[2] + red[3];
  const float inv = rsqrtf(ss * (1.0f / HID_) + 1e-6f);
  const float4 wv = reinterpret_cast<const float4*>(w)[t];
  ushort4 o;
  o.x = f32_to_bf16(v.x * inv * wv.x);
  o.y = f32_to_bf16(v.y * inv * wv.y);
  o.z = f32_to_bf16(v.z * inv * wv.z);
  o.w = f32_to_bf16(v.w * inv * wv.w);
  reinterpret_cast<ushort4*>(out + (long long)row * HID_)[t] = o;
}

// softmax over a 2048-wide fp32 row; writes P bf16 IN PLACE over the row
__global__ __launch_bounds__(256) void softmax_rows_k(float* __restrict__ scores)
{
  __shared__ float red[4];
  const long long rbase = ((long long)blockIdx.y * S_ + blockIdx.x) * S_;
  float* row = scores + rbase;
  const int t = threadIdx.x;
  float v[8];
  #pragma unroll
  for (int i = 0; i < 8; ++i) v[i] = row[t + i * 256];
  float m = v[0];
  #pragma unroll
  for (int i = 1; i < 8; ++i) m = fmaxf(m, v[i]);
  #pragma unroll
  for (int off = 32; off > 0; off >>= 1) m = fmaxf(m, __shfl_down(m, off, 64));
  if ((t & 63) == 0) red[t >> 6] = m;
  __syncthreads();
  m = fmaxf(fmaxf(red[0], red[1]), fmaxf(red[2], red[3]));
  __syncthreads();
  float s = 0.f;
  #pragma unroll
  for (int i = 0; i < 8; ++i) { v[i] = __expf(v[i] - m); s += v[i]; }
  #pragma unroll
  for (int off = 32; off > 0; off >>= 1) s += __shfl_down(s, off, 64);
  if ((t & 63) == 0) red[t >> 6] = s;
  __syncthreads();
  const float inv = 1.0f / (red[0] + red[1] + red[2] + red[3]);
  unsigned short* prow = reinterpret_cast<unsigned short*>(scores) + rbase * 2;
  #pragma unroll
  for (int i = 0; i < 8; ++i) prow[t + i * 256] = f32_to_bf16(v[i] * inv);
}

// router: fp32 rms(h1)*ln2w @ router_w + b, softmax over E=4. One wave/token.
__global__ __launch_bounds__(256) void router_k(
    const float* __restrict__ h1, const float* __restrict__ ln2w,
    const float* __restrict__ rwgt, const float* __restrict__ rbias,
    float* __restrict__ rw)
{
  const int wv = threadIdx.x >> 6, lane = threadIdx.x & 63;
  const long long m = (long long)blockIdx.x * 4 + wv;
  const float* xr = h1 + m * HID_;
  float xv[16];
  float ss = 0.f;
  #pragma unroll
  for (int i = 0; i < 16; ++i) { xv[i] = xr[lane + i * 64]; ss += xv[i] * xv[i]; }
  #pragma unroll
  for (int off = 32; off > 0; off >>= 1) ss += __shfl_down(ss, off, 64);
  ss = __shfl(ss, 0, 64);
  const float inv = rsqrtf(ss * (1.0f / HID_) + 1e-6f);
  float l0 = 0, l1 = 0, l2 = 0, l3 = 0;
  #pragma unroll
  for (int i = 0; i < 16; ++i) {
    const int k = lane + i * 64;
    const float xn = xv[i] * inv * ln2w[k];
    const float4 wr = reinterpret_cast<const float4*>(rwgt)[k];
    l0 += xn * wr.x; l1 += xn * wr.y; l2 += xn * wr.z; l3 += xn * wr.w;
  }
  #pragma unroll
  for (int off = 32; off > 0; off >>= 1) {
    l0 += __shfl_down(l0, off, 64);
    l1 += __shfl_down(l1, off, 64);
    l2 += __shfl_down(l2, off, 64);
    l3 += __shfl_down(l3, off, 64);
  }
  if (lane == 0) {
    l0 += rbias[0]; l1 += rbias[1]; l2 += rbias[2]; l3 += rbias[3];
    const float mx = fmaxf(fmaxf(l0, l1), fmaxf(l2, l3));
    const float e0 = __expf(l0 - mx), e1 = __expf(l1 - mx);
    const float e2 = __expf(l2 - mx), e3 = __expf(l3 - mx);
    const float is = 1.0f / (e0 + e1 + e2 + e3);
    reinterpret_cast<float4*>(rw)[m] = make_float4(e0 * is, e1 * is, e2 * is, e3 * is);
  }
}

// balance loss: single block, deterministic
__global__ __launch_bounds__(256) void balance_k(const float* __restrict__ rw,
                                                 float* __restrict__ out_scalar)
{
  __shared__ float red[4];
  float acc = 0.f;
  for (int it = threadIdx.x; it < S_ * E_; it += 256) {
    const int s = it >> 2, e = it & 3;
    float mr = 0.f;
    #pragma unroll
    for (int b = 0; b < B_; ++b) mr += rw[((long long)b * S_ + s) * E_ + e];
    mr *= (1.0f / B_);
    const float d = mr - 1.0f / E_;
    acc += d * d;
  }
  #pragma unroll
  for (int off = 32; off > 0; off >>= 1) acc += __shfl_down(acc, off, 64);
  if ((threadIdx.x & 63) == 0) red[threadIdx.x >> 6] = acc;
  __syncthreads();
  if (threadIdx.x == 0)
    out_scalar[0] = (red[0] + red[1] + red[2] + red[3]) * (0.01f / (S_ * E_));
}

extern "C" void kernel_launch(void* const* d_in, const int* in_sizes, int n_in,
                              void* d_out, int out_size, void* d_ws, size_t ws_size,
                              hipStream_t stream)
{
  const float* hidden   = (const float*)d_in[0];
  const float* ln1w     = (const float*)d_in[1];
  const float* wq       = (const float*)d_in[2];
  const float* wk       = (const float*)d_in[3];
  const float* wv       = (const float*)d_in[4];
  const float* wo       = (const float*)d_in[5];
  const float* ln2w     = (const float*)d_in[6];
  const float* router_w = (const float*)d_in[7];
  const float* router_b = (const float*)d_in[8];
  const float* gate_w   = (const float*)d_in[9];
  const float* up_w     = (const float*)d_in[10];
  const float* down_w   = (const float*)d_in[11];
  float* out = (float*)d_out;   // h1 lives here; MoE accumulates in place

  // ---- lean workspace layout: ~136 MiB total ----
  char* ws = (char*)d_ws;
  size_t off = 0;
  auto carve = [&](size_t bytes) {
    off = (off + 255) & ~(size_t)255;
    char* p = ws + off;
    off += bytes;
    return p;
  };
  unsigned short* wqT   = (unsigned short*)carve((size_t)HID_ * HID_ * 2);  // 2 MiB
  unsigned short* wkT   = (unsigned short*)carve((size_t)HID_ * HID_ * 2);
  unsigned short* wvT   = (unsigned short*)carve((size_t)HID_ * HID_ * 2);
  unsigned short* woT   = (unsigned short*)carve((size_t)HID_ * HID_ * 2);
  unsigned short* x_bf  = (unsigned short*)carve((size_t)M_ * HID_ * 2);    // 16 MiB, reused as o_bf
  unsigned short* qb    = (unsigned short*)carve((size_t)M_ * HID_ * 2);    // 16 MiB, reused as x2_bf
  unsigned short* kb    = (unsigned short*)carve((size_t)M_ * HID_ * 2);    // 16 MiB \ reused as gu (32 MiB)
  unsigned short* vT    = (unsigned short*)carve((size_t)M_ * HID_ * 2);    // 16 MiB /
  float*          rwbuf = (float*)carve((size_t)M_ * E_ * 4);               // 128 KiB
  char*           ubase = carve((size_t)NHG_ * S_ * S_ * 4);                // 64 MiB union
  float*          scores = (float*)ubase;
  unsigned short* gateT = (unsigned short*)(ubase);                          // 16 MiB
  unsigned short* upT   = (unsigned short*)(ubase + (size_t)16 * 1024 * 1024);
  unsigned short* downT = (unsigned short*)(ubase + (size_t)32 * 1024 * 1024);
  unsigned short* o_bf  = x_bf;
  unsigned short* x2_bf = qb;
  unsigned short* gu    = kb;   // spans kb+vT = 32 MiB

  const dim3 blk256(256), blkT(32, 8);

  // 1) attention weights -> bf16 B^T
  transpose_cast_k<<<dim3(32, 32, 1), blkT, 0, stream>>>(wq, wqT, HID_, HID_);
  transpose_cast_k<<<dim3(32, 32, 1), blkT, 0, stream>>>(wk, wkT, HID_, HID_);
  transpose_cast_k<<<dim3(32, 32, 1), blkT, 0, stream>>>(wv, wvT, HID_, HID_);
  transpose_cast_k<<<dim3(32, 32, 1), blkT, 0, stream>>>(wo, woT, HID_, HID_);

  // 2) x = bf16(rms(hidden, ln1_w))
  rmsnorm_cast_k<<<M_, blk256, 0, stream>>>(hidden, ln1w, x_bf);

  // 3) Q/K with fused elu+1, V written transposed
  {
    EpiAux a{}; a.c_bf16 = qb; a.ldc = HID_;
    gemm_bf16k<EPI_ELU_BF16><<<dim3(8, 64, 1), blk256, 0, stream>>>(
        x_bf, HID_, 0, 0, 0, wqT, HID_, 0, 0, 0, 0, 0, 0, HID_, a);
  }
  {
    EpiAux a{}; a.c_bf16 = kb; a.ldc = HID_;
    gemm_bf16k<EPI_ELU_BF16><<<dim3(8, 64, 1), blk256, 0, stream>>>(
        x_bf, HID_, 0, 0, 0, wkT, HID_, 0, 0, 0, 0, 0, 0, HID_, a);
  }
  {
    EpiAux a{}; a.c_bf16 = vT;
    gemm_bf16k<EPI_VT><<<dim3(8, 64, 1), blk256, 0, stream>>>(
        x_bf, HID_, 0, 0, 0, wvT, HID_, 0, 0, 0, 0, 0, 0, HID_, a);
  }

  // 4) attention, NHG_=4 heads per group; scores slab reused per group
  for (int grp = 0; grp < 16 / NHG_; ++grp) {
    EpiAux as{}; as.c_f32 = scores; as.ldc = S_; as.strideCz = (long long)S_ * S_;
    gemm_bf16k<EPI_F32><<<dim3(16, 16, NHG_), blk256, 0, stream>>>(
        qb, HID_, (long long)S_ * HID_, HD_, grp * NHG_,
        kb, HID_, (long long)S_ * HID_, HD_, grp * NHG_,
        2, 3, 0, HD_, as);
    softmax_rows_k<<<dim3(S_, NHG_, 1), blk256, 0, stream>>>(scores);
    EpiAux ap{}; ap.c_bf16 = o_bf;
    gemm_bf16k<EPI_PV_O><<<dim3(2, 16, NHG_), blk256, 0, stream>>>(
        (const unsigned short*)scores, 2 * S_, (long long)S_ * 2 * S_, 0, 0,
        vT, S_, (long long)HD_ * S_, 0, grp * NHG_,
        0, 0, grp * NHG_, S_, ap);
  }

  // 5) MoE weights -> bf16 B^T, into the now-dead scores slab
  transpose_cast_k<<<dim3(64, 32, E_), blkT, 0, stream>>>(gate_w, gateT, HID_, IM_);
  transpose_cast_k<<<dim3(64, 32, E_), blkT, 0, stream>>>(up_w,   upT,   HID_, IM_);
  transpose_cast_k<<<dim3(32, 64, E_), blkT, 0, stream>>>(down_w, downT, IM_, HID_);

  // 6) h1 = hidden + O @ wo, written straight into d_out
  {
    EpiAux a{}; a.add_src = hidden; a.out2 = out;
    gemm_bf16k<EPI_WO><<<dim3(8, 64, 1), blk256, 0, stream>>>(
        o_bf, HID_, 0, 0, 0, woT, HID_, 0, 0, 0, 0, 0, 0, HID_, a);
  }

  // 7) x2 = bf16(rms(h1, ln2_w)); router (fp32); balance loss scalar
  rmsnorm_cast_k<<<M_, blk256, 0, stream>>>(out, ln2w, x2_bf);
  router_k<<<M_ / 4, blk256, 0, stream>>>(out, ln2w, router_w, router_b, rwbuf);
  balance_k<<<1, blk256, 0, stream>>>(rwbuf, out + (size_t)M_ * HID_);

  // 8) dense MoE per expert: fused gate+up -> gu; down -> out += acc*rw
  for (int i = 0; i < E_; ++i) {
    gemm_gu_k<<<dim3(16, 64, 1), blk256, 0, stream>>>(
        x2_bf, gateT + (size_t)i * IM_ * HID_, upT + (size_t)i * IM_ * HID_, gu);
    EpiAux ad{}; ad.out2 = out; ad.rw = rwbuf; ad.expert = i;
    gemm_bf16k<EPI_DOWN><<<dim3(8, 64, 1), blk256, 0, stream>>>(
        gu, IM_, 0, 0, 0, downT + (size_t)i * HID_ * IM_, IM_, 0, 0, 0,
        0, 0, 0, IM_, ad);
  }
}